// Round 1
// baseline (582.610 us; speedup 1.0000x reference)
//
#include <hip/hip_runtime.h>
#include <hip/hip_bf16.h>
#include <stdint.h>

#define T_NUM 1024
#define H_DIM 2048
#define E_NUM 16
#define TOPK 4
#define I_DIM 1408
#define SHI_DIM 2816

typedef __attribute__((ext_vector_type(4))) float f32x4;
typedef __attribute__((ext_vector_type(8))) short bf16x8;
typedef __attribute__((ext_vector_type(4))) short s16x4;

static __device__ __forceinline__ short f2bf(float f) {
    __hip_bfloat16 h = __float2bfloat16(f);
    return __builtin_bit_cast(short, h);
}

// ---------------- router: fp32 logits -> softmax -> top4 ----------------
__global__ void router_kernel(const float* __restrict__ x, const float* __restrict__ wgate,
                              int* __restrict__ top_e, float* __restrict__ top_w) {
    const int t = blockIdx.x;
    const int tid = threadIdx.x;       // 256 threads
    __shared__ float xsh[H_DIM];
    const float* xr = x + (size_t)t * H_DIM;
    for (int h = tid; h < H_DIM; h += 256) xsh[h] = xr[h];
    __syncthreads();

    const int e = tid >> 4;            // 0..15
    const int j = tid & 15;
    const float* wr = wgate + (size_t)e * H_DIM;
    float acc = 0.f;
    for (int h = j; h < H_DIM; h += 16) acc += xsh[h] * wr[h];
    #pragma unroll
    for (int m = 8; m >= 1; m >>= 1) acc += __shfl_down(acc, m, 16);

    __shared__ float logits[E_NUM];
    if (j == 0) logits[e] = acc;
    __syncthreads();

    if (tid == 0) {
        float mx = logits[0];
        #pragma unroll
        for (int i = 1; i < E_NUM; ++i) mx = fmaxf(mx, logits[i]);
        float p[E_NUM]; float s = 0.f;
        #pragma unroll
        for (int i = 0; i < E_NUM; ++i) { p[i] = expf(logits[i] - mx); s += p[i]; }
        const float inv = 1.f / s;
        #pragma unroll
        for (int i = 0; i < E_NUM; ++i) p[i] *= inv;
        for (int k = 0; k < TOPK; ++k) {
            float best = -1.f; int bi = 0;
            #pragma unroll
            for (int i = 0; i < E_NUM; ++i) if (p[i] > best) { best = p[i]; bi = i; }
            top_e[t * TOPK + k] = bi;
            top_w[t * TOPK + k] = best;
            p[bi] = -2.f;
        }
    }
}

// ------- stable bucket sort of 4096 slots by expert (deterministic) -------
__global__ void perm_kernel(const int* __restrict__ top_e,
                            int* __restrict__ offs, int* __restrict__ perm) {
    __shared__ int cnt[256][E_NUM];
    __shared__ int base[E_NUM];
    const int tid = threadIdx.x;
    int c[E_NUM];
    #pragma unroll
    for (int i = 0; i < E_NUM; ++i) c[i] = 0;
    for (int s = tid * 16; s < tid * 16 + 16; ++s) c[top_e[s]]++;
    #pragma unroll
    for (int i = 0; i < E_NUM; ++i) cnt[tid][i] = c[i];
    __syncthreads();
    if (tid < E_NUM) {
        int run = 0;
        for (int b = 0; b < 256; ++b) { int v = cnt[b][tid]; cnt[b][tid] = run; run += v; }
        base[tid] = run;               // per-expert total
    }
    __syncthreads();
    if (tid == 0) {
        int run = 0;
        for (int e2 = 0; e2 < E_NUM; ++e2) { int v = base[e2]; base[e2] = run; offs[e2] = run; run += v; }
        offs[E_NUM] = run;             // = 4096
    }
    __syncthreads();
    int run[E_NUM];
    #pragma unroll
    for (int i = 0; i < E_NUM; ++i) run[i] = base[i] + cnt[tid][i];
    for (int s = tid * 16; s < tid * 16 + 16; ++s) {
        int e2 = top_e[s];
        perm[run[e2]++] = s;
    }
}

// ---------------- GEMM template ----------------
// MODE 0: routed SwiGLU  : A=x gathered by token, B=wg[e],wu[e], out=act_r[slot]
// MODE 1: shared SwiGLU  : A=x dense,            B=sg,su,       out=act_s[row]
// MODE 2: routed down    : A=act_r gathered,     B=wd[e], out=atomicAdd(out[token]) * w
// MODE 3: shared down    : A=act_s dense,        B=sd,    out=plain store out[row]
template<int MODE>
__global__ __launch_bounds__(256, 2) void moe_gemm(
    const float* __restrict__ A, int lda, int Kdim,
    const float* __restrict__ B1g, const float* __restrict__ B2g, int ldb,
    float* __restrict__ Out, int ldo,
    const int* __restrict__ perm, const int* __restrict__ offs,
    const float* __restrict__ top_w)
{
    constexpr int NB = (MODE == 0 || MODE == 1) ? 2 : 1;
    constexpr int BM = 128, BN = 128, BK = 32, KP = 40;  // KP pad keeps b128 reads ~2-way
    __shared__ short As[2][BM * KP];
    __shared__ short Bs[2][NB * BN * KP];
    __shared__ int   rows_a[BM];
    __shared__ int   rows_o[BM];
    __shared__ float w_m[BM];

    const int tid = threadIdx.x;
    const int nt = blockIdx.x, mt = blockIdx.y, e = blockIdx.z;

    int off = 0, cnt = T_NUM;
    const float* B1 = B1g;
    const float* B2 = B2g;
    if constexpr (MODE == 0) {
        off = offs[e]; cnt = offs[e + 1] - off;
        if (mt * BM >= cnt) return;
        B1 = B1g + (size_t)e * H_DIM * I_DIM;
        B2 = B2g + (size_t)e * H_DIM * I_DIM;
    }
    if constexpr (MODE == 2) {
        off = offs[e]; cnt = offs[e + 1] - off;
        if (mt * BM >= cnt) return;
        B1 = B1g + (size_t)e * I_DIM * H_DIM;
    }

    if (tid < BM) {
        const int gm = mt * BM + tid;
        if constexpr (MODE == 0) {
            int s = perm[off + (gm < cnt ? gm : cnt - 1)];
            rows_a[tid] = s >> 2; rows_o[tid] = s; w_m[tid] = 1.f;
        } else if constexpr (MODE == 2) {
            int s = perm[off + (gm < cnt ? gm : cnt - 1)];
            rows_a[tid] = s; rows_o[tid] = s >> 2; w_m[tid] = top_w[s];
        } else {
            rows_a[tid] = gm; rows_o[tid] = gm; w_m[tid] = 1.f;
        }
    }
    __syncthreads();

    f32x4 aReg[4];
    float bReg[NB][4][4];

    auto gload = [&](int kt) {
        const int k0 = kt * BK;
        #pragma unroll
        for (int it = 0; it < 4; ++it) {
            const int q = it * 256 + tid;
            const int m = q >> 3, kq = (q & 7) * 4;
            aReg[it] = *reinterpret_cast<const f32x4*>(A + (size_t)rows_a[m] * lda + k0 + kq);
        }
        #pragma unroll
        for (int it = 0; it < 4; ++it) {
            const int q = it * 256 + tid;
            const int n = q & 127, kb = (q >> 7) * 4;
            const float* p1 = B1 + (size_t)(k0 + kb) * ldb + (size_t)nt * BN + n;
            #pragma unroll
            for (int dk = 0; dk < 4; ++dk) bReg[0][it][dk] = p1[(size_t)dk * ldb];
            if constexpr (NB == 2) {
                const float* p2 = B2 + (size_t)(k0 + kb) * ldb + (size_t)nt * BN + n;
                #pragma unroll
                for (int dk = 0; dk < 4; ++dk) bReg[1][it][dk] = p2[(size_t)dk * ldb];
            }
        }
    };

    auto swrite = [&](int buf) {
        #pragma unroll
        for (int it = 0; it < 4; ++it) {
            const int q = it * 256 + tid;
            const int m = q >> 3, kq = (q & 7) * 4;
            s16x4 v = { f2bf(aReg[it][0]), f2bf(aReg[it][1]), f2bf(aReg[it][2]), f2bf(aReg[it][3]) };
            *reinterpret_cast<s16x4*>(&As[buf][m * KP + kq]) = v;
        }
        #pragma unroll
        for (int it = 0; it < 4; ++it) {
            const int q = it * 256 + tid;
            const int n = q & 127, kb = (q >> 7) * 4;
            #pragma unroll
            for (int mat = 0; mat < NB; ++mat) {
                s16x4 v = { f2bf(bReg[mat][it][0]), f2bf(bReg[mat][it][1]),
                            f2bf(bReg[mat][it][2]), f2bf(bReg[mat][it][3]) };
                *reinterpret_cast<s16x4*>(&Bs[buf][mat * BN * KP + n * KP + kb]) = v;
            }
        }
    };

    f32x4 acc1[4][4], acc2[4][4];
    #pragma unroll
    for (int i = 0; i < 4; ++i)
        #pragma unroll
        for (int j = 0; j < 4; ++j) { acc1[i][j] = (f32x4)0.f; acc2[i][j] = (f32x4)0.f; }

    const int lane = tid & 63;
    const int wr = (tid >> 6) >> 1, wc = (tid >> 6) & 1;
    const int lrow = lane & 15;
    const int lko = (lane >> 4) * 8;

    auto compute = [&](int buf) {
        bf16x8 af[4];
        #pragma unroll
        for (int mi = 0; mi < 4; ++mi)
            af[mi] = *reinterpret_cast<const bf16x8*>(&As[buf][(wr * 64 + mi * 16 + lrow) * KP + lko]);
        #pragma unroll
        for (int ni = 0; ni < 4; ++ni) {
            const int brow = (wc * 64 + ni * 16 + lrow) * KP + lko;
            bf16x8 b1 = *reinterpret_cast<const bf16x8*>(&Bs[buf][brow]);
            #pragma unroll
            for (int mi = 0; mi < 4; ++mi)
                acc1[mi][ni] = __builtin_amdgcn_mfma_f32_16x16x32_bf16(af[mi], b1, acc1[mi][ni], 0, 0, 0);
            if constexpr (NB == 2) {
                bf16x8 b2 = *reinterpret_cast<const bf16x8*>(&Bs[buf][BN * KP + brow]);
                #pragma unroll
                for (int mi = 0; mi < 4; ++mi)
                    acc2[mi][ni] = __builtin_amdgcn_mfma_f32_16x16x32_bf16(af[mi], b2, acc2[mi][ni], 0, 0, 0);
            }
        }
    };

    const int NK = Kdim / BK;
    gload(0);
    int cur = 0;
    for (int kt = 0; kt < NK; ++kt) {
        swrite(cur);
        __syncthreads();
        if (kt + 1 < NK) gload(kt + 1);
        compute(cur);
        cur ^= 1;
    }

    // epilogue
    #pragma unroll
    for (int mi = 0; mi < 4; ++mi) {
        #pragma unroll
        for (int j = 0; j < 4; ++j) {
            const int ml = wr * 64 + mi * 16 + (lane >> 4) * 4 + j;
            const int gm = mt * BM + ml;
            if constexpr (MODE == 0 || MODE == 2) { if (gm >= cnt) continue; }
            const int orow = rows_o[ml];
            const float wsc = w_m[ml];
            #pragma unroll
            for (int ni = 0; ni < 4; ++ni) {
                const int n = nt * BN + wc * 64 + ni * 16 + (lane & 15);
                const float v1 = acc1[mi][ni][j];
                if constexpr (NB == 2) {
                    const float u = acc2[mi][ni][j];
                    const float s = v1 / (1.f + __expf(-v1));   // silu(g)
                    Out[(size_t)orow * ldo + n] = s * u;
                } else if constexpr (MODE == 2) {
                    atomicAdd(&Out[(size_t)orow * ldo + n], v1 * wsc);
                } else {
                    Out[(size_t)orow * ldo + n] = v1;
                }
            }
        }
    }
}

extern "C" void kernel_launch(void* const* d_in, const int* in_sizes, int n_in,
                              void* d_out, int out_size, void* d_ws, size_t ws_size,
                              hipStream_t stream) {
    const float* x     = (const float*)d_in[0];
    const float* wgate = (const float*)d_in[1];
    const float* wg    = (const float*)d_in[2];
    const float* wu    = (const float*)d_in[3];
    const float* wd    = (const float*)d_in[4];
    const float* sg    = (const float*)d_in[5];
    const float* su    = (const float*)d_in[6];
    const float* sd    = (const float*)d_in[7];
    float* out = (float*)d_out;

    uintptr_t p = (uintptr_t)d_ws;
    auto alloc = [&](size_t bytes) {
        p = (p + 255) & ~(uintptr_t)255;
        void* r = (void*)p; p += bytes; return r;
    };
    int*   top_e = (int*)alloc((size_t)T_NUM * TOPK * sizeof(int));
    float* top_w = (float*)alloc((size_t)T_NUM * TOPK * sizeof(float));
    int*   offs  = (int*)alloc((E_NUM + 1) * sizeof(int));
    int*   perm  = (int*)alloc((size_t)T_NUM * TOPK * sizeof(int));
    float* act_r = (float*)alloc((size_t)T_NUM * TOPK * I_DIM * sizeof(float));   // 23.1 MB
    float* act_s = (float*)alloc((size_t)T_NUM * SHI_DIM * sizeof(float));        // 11.5 MB

    router_kernel<<<T_NUM, 256, 0, stream>>>(x, wgate, top_e, top_w);
    perm_kernel<<<1, 256, 0, stream>>>(top_e, offs, perm);

    // shared SwiGLU: act_s = silu(x@sg)*(x@su)
    moe_gemm<1><<<dim3(SHI_DIM / 128, T_NUM / 128, 1), 256, 0, stream>>>(
        x, H_DIM, H_DIM, sg, su, SHI_DIM, act_s, SHI_DIM, nullptr, nullptr, nullptr);
    // shared down: out = act_s @ sd   (plain stores initialize all of out)
    moe_gemm<3><<<dim3(H_DIM / 128, T_NUM / 128, 1), 256, 0, stream>>>(
        act_s, SHI_DIM, SHI_DIM, sd, nullptr, H_DIM, out, H_DIM, nullptr, nullptr, nullptr);
    // routed SwiGLU per expert (gathered rows of x)
    moe_gemm<0><<<dim3(I_DIM / 128, T_NUM / 128, E_NUM), 256, 0, stream>>>(
        x, H_DIM, H_DIM, wg, wu, I_DIM, act_r, I_DIM, perm, offs, nullptr);
    // routed down per expert: out[token] += w * (act_r[slot] @ wd[e])
    moe_gemm<2><<<dim3(H_DIM / 128, T_NUM / 128, E_NUM), 256, 0, stream>>>(
        act_r, I_DIM, I_DIM, wd, nullptr, H_DIM, out, H_DIM, perm, offs, top_w);
}